// Round 16
// baseline (834.893 us; speedup 1.0000x reference)
//
#include <hip/hip_runtime.h>
#include <hip/hip_bf16.h>

#define T_TOK 8192
#define D_DIM 1024
#define F_DIM 4096
#define E_NUM 8

typedef short s16x8 __attribute__((ext_vector_type(8)));
typedef float f32x4 __attribute__((ext_vector_type(4)));
typedef unsigned short u16x8 __attribute__((ext_vector_type(8)));

__device__ __forceinline__ unsigned short f2bf(float f) {
  union { float f; unsigned int u; } v; v.f = f;
  unsigned int u = v.u;
  return (unsigned short)((u + 0x7FFFu + ((u >> 16) & 1u)) >> 16);  // RNE
}

__device__ __forceinline__ void async16(const void* g, void* l) {
  __builtin_amdgcn_global_load_lds((const __attribute__((address_space(1))) void*)g,
                                   (__attribute__((address_space(3))) void*)l, 16, 0, 0);
}

// ---- pre-pass: blocks 0..16383 = w1/w3 transpose; 16384.. = RMSNorm+router ----
__global__ __launch_bounds__(256) void prepass_kernel(
    const float* __restrict__ hs, const float* __restrict__ nw,
    const float* __restrict__ gw, const float* __restrict__ w1,
    const float* __restrict__ w3, unsigned short* __restrict__ xb,
    unsigned short* __restrict__ w13t, float* __restrict__ logits_out,
    int* __restrict__ cnt, int* __restrict__ ilist, float* __restrict__ wlist) {
  __shared__ unsigned short tileS[64][72];
  __shared__ float red[4];
  __shared__ float pl[4][8];
  int bx = blockIdx.x;
  int tid = threadIdx.x;
  if (bx < 16384) {
    int tensor = bx >> 13;           // 0 = w1, 1 = w3
    int e = (bx >> 10) & 7;
    int tl = bx & 1023;
    const float* src = (tensor == 0 ? w1 : w3) + (size_t)e * D_DIM * F_DIM;
    int tr = tl >> 6, tc = tl & 63;
    int r0 = tr * 64, c0 = tc * 64;
    int rr = tid >> 4, ccb = (tid & 15) * 4;
#pragma unroll
    for (int i = 0; i < 4; ++i) {
      int r = rr + i * 16;
      float4 v = *(const float4*)(src + (size_t)(r0 + r) * F_DIM + c0 + ccb);
      tileS[ccb + 0][r] = f2bf(v.x);
      tileS[ccb + 1][r] = f2bf(v.y);
      tileS[ccb + 2][r] = f2bf(v.z);
      tileS[ccb + 3][r] = f2bf(v.w);
    }
    __syncthreads();
    int row = tid >> 2, col = (tid & 3) * 16;
    int f = c0 + row;
    int prow = ((f >> 5) * 64) + (f & 31) + (tensor == 1 ? 32 : 0);
    unsigned short* dp = w13t + ((size_t)e * 8192 + prow) * D_DIM + r0 + col;
    u16x8 v0, v1;
#pragma unroll
    for (int j = 0; j < 8; ++j) { v0[j] = tileS[row][col + j]; v1[j] = tileS[row][col + 8 + j]; }
    *(u16x8*)dp = v0;
    *(u16x8*)(dp + 8) = v1;
  } else {
    int t = bx - 16384;
    int lane = tid & 63, wid = tid >> 6;
    float4 v = ((const float4*)(hs + (size_t)t * D_DIM))[tid];
    float ss = v.x * v.x + v.y * v.y + v.z * v.z + v.w * v.w;
#pragma unroll
    for (int o = 32; o > 0; o >>= 1) ss += __shfl_xor(ss, o);
    if (lane == 0) red[wid] = ss;
    __syncthreads();
    float ms = (red[0] + red[1] + red[2] + red[3]) * (1.0f / 1024.0f);
    float rs = rsqrtf(ms + 1e-6f);
    float4 wv = ((const float4*)nw)[tid];
    float x0 = v.x * rs * wv.x, x1 = v.y * rs * wv.y;
    float x2 = v.z * rs * wv.z, x3 = v.w * rs * wv.w;
    ((ushort4*)(xb + (size_t)t * D_DIM))[tid] =
        make_ushort4(f2bf(x0), f2bf(x1), f2bf(x2), f2bf(x3));
    float p[8];
#pragma unroll
    for (int e = 0; e < 8; ++e) {
      float4 g = ((const float4*)(gw + (size_t)e * D_DIM))[tid];
      p[e] = x0 * g.x + x1 * g.y + x2 * g.z + x3 * g.w;
    }
#pragma unroll
    for (int e = 0; e < 8; ++e) {
#pragma unroll
      for (int o = 32; o > 0; o >>= 1) p[e] += __shfl_xor(p[e], o);
    }
    if (lane == 0) {
#pragma unroll
      for (int e = 0; e < 8; ++e) pl[wid][e] = p[e];
    }
    __syncthreads();
    if (tid == 0) {
      float l[8];
#pragma unroll
      for (int e = 0; e < 8; ++e) {
        l[e] = pl[0][e] + pl[1][e] + pl[2][e] + pl[3][e];
        logits_out[(size_t)t * 8 + e] = l[e];
      }
      int i0 = 0; float b0 = l[0];
#pragma unroll
      for (int e = 1; e < 8; ++e) if (l[e] > b0) { b0 = l[e]; i0 = e; }
      int i1 = (i0 == 0) ? 1 : 0; float b1 = l[i1];
#pragma unroll
      for (int e = 0; e < 8; ++e) if (e != i0 && l[e] > b1) { b1 = l[e]; i1 = e; }
      float wa = 1.0f / (1.0f + __expf(b1 - b0));
      float wb = 1.0f / (1.0f + __expf(b0 - b1));
      int p0 = atomicAdd(&cnt[i0], 1);
      ilist[i0 * T_TOK + p0] = t * 2;     wlist[i0 * T_TOK + p0] = wa;
      int p1 = atomicAdd(&cnt[i1], 1);
      ilist[i1 * T_TOK + p1] = t * 2 + 1; wlist[i1 * T_TOK + p1] = wb;
    }
  }
}

// ---- GEMM1: H = silu(Xe@W1e)*(Xe@W3e), compacted-H. Idle tail blocks
// ---- transpose w2 -> w2t (2 x 64x64 tiles per block, 256 threads each).
__global__ __launch_bounds__(512, 2) void gemm1_kernel(
    const unsigned short* __restrict__ xb, const unsigned short* __restrict__ w13t,
    unsigned short* __restrict__ H, const int* __restrict__ cnt,
    const int* __restrict__ ilist, const float* __restrict__ w2,
    unsigned short* __restrict__ w2t) {
  int flat = blockIdx.x;       // 8192 blocks
  int e = flat & 7;            // expert == XCD
  int widx = flat >> 3;        // 0..1023
  int ne = cnt[e];
  int art = (ne + 255) >> 8;   // active row-tiles (<=32)
  int tid = threadIdx.x, lane = tid & 63, w = tid >> 6;
  __shared__ __align__(16) unsigned short As[3 * 8192];  // [3][256][32]
  __shared__ __align__(16) unsigned short Bs[3 * 8192];
  __shared__ int toks[256];
  if (widx >= (art << 5)) {
    // ---- idle block: dense idle index -> w2 transpose tiles ----
    int idle_before = 0;
#pragma unroll
    for (int j = 0; j < E_NUM; ++j) {
      int aj = (cnt[j] + 255) >> 8;
      idle_before += (j < e) ? (1024 - (aj << 5)) : 0;
    }
    int my_idle = idle_before + (widx - (art << 5));
    if (my_idle >= 4096) return;
    int h = tid >> 8, tid2 = tid & 255;
    unsigned short* ts = (unsigned short*)As + h * 4608;  // [64][72]
    int tileIdx = my_idle * 2 + h;                        // 0..8191
    int e2 = tileIdx >> 10, tl = tileIdx & 1023;
    int tr = tl >> 4, tc = tl & 15;
    const float* src = w2 + (size_t)e2 * F_DIM * D_DIM;
    int r0 = tr * 64, c0 = tc * 64;    // r over F, c over D
    int rr = tid2 >> 4, ccb = (tid2 & 15) * 4;
#pragma unroll
    for (int i = 0; i < 4; ++i) {
      int r = rr + i * 16;
      float4 v = *(const float4*)(src + (size_t)(r0 + r) * D_DIM + c0 + ccb);
      ts[(ccb + 0) * 72 + r] = f2bf(v.x);
      ts[(ccb + 1) * 72 + r] = f2bf(v.y);
      ts[(ccb + 2) * 72 + r] = f2bf(v.z);
      ts[(ccb + 3) * 72 + r] = f2bf(v.w);
    }
    __syncthreads();
    int row = tid2 >> 2, col = (tid2 & 3) * 16;
    unsigned short* dp = w2t + ((size_t)e2 * D_DIM + c0 + row) * F_DIM + r0 + col;
    u16x8 v0, v1;
#pragma unroll
    for (int j = 0; j < 8; ++j) { v0[j] = ts[row * 72 + col + j]; v1[j] = ts[row * 72 + col + 8 + j]; }
    *(u16x8*)dp = v0;
    *(u16x8*)(dp + 8) = v1;
    return;
  }
  int rt = widx % art;         // rt-fast: rt blocks share each B-slice
  int ft = widx / art;         // 0..31
  int r0 = rt * 256;
  int hbase = 0;               // compacted-H base = prefix sum of cnt
#pragma unroll
  for (int j = 0; j < E_NUM; ++j) hbase += (j < e) ? cnt[j] : 0;
  if (tid < 256) toks[tid] = ilist[e * T_TOK + min(r0 + tid, ne - 1)];
  __syncthreads();
  const unsigned short* bpanel = w13t + ((size_t)e * 8192 + ft * 256) * D_DIM;
  int sr0 = tid >> 2, sr1 = sr0 + 128;
  int ch0 = (((tid & 3) ^ ((sr0 >> 1) & 3)) * 8);
  int ch1 = (((tid & 3) ^ ((sr1 >> 1) & 3)) * 8);
  const unsigned short* ap0 = xb + (size_t)(toks[sr0] >> 1) * D_DIM + ch0;
  const unsigned short* ap1 = xb + (size_t)(toks[sr1] >> 1) * D_DIM + ch1;
  const unsigned short* bp0 = bpanel + (size_t)sr0 * D_DIM + ch0;
  const unsigned short* bp1 = bpanel + (size_t)sr1 * D_DIM + ch1;
  int d0 = (sr0 * 32) + (tid & 3) * 8;
  int d1 = d0 + 4096;
  int wr = w >> 2, wc = w & 3;           // 2 x 4 wave grid
  int lr = lane & 15, lc = lane >> 4;
  int aoff[8], boff[4];
#pragma unroll
  for (int m = 0; m < 8; ++m) {
    int row = wr * 128 + m * 16 + lr;
    aoff[m] = row * 32 + ((lc ^ ((row >> 1) & 3)) * 8);
  }
#pragma unroll
  for (int n = 0; n < 4; ++n) {
    int row = wc * 64 + n * 16 + lr;
    boff[n] = row * 32 + ((lc ^ ((row >> 1) & 3)) * 8);
  }
  f32x4 acc[8][4] = {};
  async16(ap0, &As[d0]); async16(ap1, &As[d1]);
  async16(bp0, &Bs[d0]); async16(bp1, &Bs[d1]);
  async16(ap0 + 32, &As[8192 + d0]); async16(ap1 + 32, &As[8192 + d1]);
  async16(bp0 + 32, &Bs[8192 + d0]); async16(bp1 + 32, &Bs[8192 + d1]);

#define G1_STEP(T_, BUF_, VMC_, DOST_)                                          \
  {                                                                             \
    asm volatile("s_waitcnt vmcnt(" VMC_ ")" ::: "memory");                     \
    __builtin_amdgcn_s_barrier();                                               \
    const unsigned short* Ab = &As[(BUF_) * 8192];                              \
    const unsigned short* Bb = &Bs[(BUF_) * 8192];                              \
    s16x8 a[8], b[4];                                                           \
    if (DOST_) { /* phase 1 stage: A of t+2 */                                  \
      int nk = ((T_) + 2) * 32;                                                 \
      async16(ap0 + nk, &As[(((BUF_) + 2) % 3) * 8192 + d0]);                   \
      async16(ap1 + nk, &As[(((BUF_) + 2) % 3) * 8192 + d1]);                   \
    }                                                                           \
    _Pragma("unroll") for (int m = 0; m < 4; ++m)                               \
        a[m] = *(const s16x8*)(Ab + aoff[m]);                                   \
    _Pragma("unroll") for (int n = 0; n < 4; ++n)                               \
        b[n] = *(const s16x8*)(Bb + boff[n]);                                   \
    __builtin_amdgcn_s_setprio(1);                                              \
    _Pragma("unroll") for (int m = 0; m < 4; ++m)                               \
        _Pragma("unroll") for (int n = 0; n < 4; ++n)                           \
            acc[m][n] = __builtin_amdgcn_mfma_f32_16x16x32_bf16(                \
                a[m], b[n], acc[m][n], 0, 0, 0);                                \
    __builtin_amdgcn_s_setprio(0);                                              \
    if (DOST_) { /* phase 2 stage: B of t+2 */                                  \
      int nk = ((T_) + 2) * 32;                                                 \
      async16(bp0 + nk, &Bs[(((BUF_) + 2) % 3) * 8192 + d0]);                   \
      async16(bp1 + nk, &Bs[(((BUF_) + 2) % 3) * 8192 + d1]);                   \
    }                                                                           \
    _Pragma("unroll") for (int m = 4; m < 8; ++m)                               \
        a[m] = *(const s16x8*)(Ab + aoff[m]);                                   \
    __builtin_amdgcn_s_setprio(1);                                              \
    _Pragma("unroll") for (int m = 4; m < 8; ++m)                               \
        _Pragma("unroll") for (int n = 0; n < 4; ++n)                           \
            acc[m][n] = __builtin_amdgcn_mfma_f32_16x16x32_bf16(                \
                a[m], b[n], acc[m][n], 0, 0, 0);                                \
    __builtin_amdgcn_s_setprio(0);                                              \
  }

  for (int tb = 0; tb < 30; tb += 3) {
    G1_STEP(tb, 0, "4", 1)
    G1_STEP(tb + 1, 1, "4", 1)
    G1_STEP(tb + 2, 2, "4", 1)
  }
  G1_STEP(30, 0, "4", 0)
  G1_STEP(31, 1, "0", 0)
#undef G1_STEP

  int g4 = lane >> 4, cl = lane & 15;
  int fbase = (4 * ft + wc) * 32;   // 32 f-cols per wave (w1 n=0,1 ; w3 n=2,3)
#pragma unroll
  for (int m = 0; m < 8; ++m) {
#pragma unroll
    for (int j = 0; j < 4; ++j) {
      int rloc = wr * 128 + m * 16 + g4 * 4 + j;
      if (r0 + rloc < ne) {
        unsigned short* hp = H + (size_t)(hbase + r0 + rloc) * F_DIM + fbase + cl;
#pragma unroll
        for (int n = 0; n < 2; ++n) {
          float c1 = acc[m][n][j], c3 = acc[m][n + 2][j];
          float h = c1 / (1.0f + __expf(-c1)) * c3;
          hp[n * 16] = f2bf(h);
        }
      }
    }
  }
}

// ---- GEMM2: P[slot] = w * (He @ W2e). Plain stores, no atomics ----
__global__ __launch_bounds__(512, 2) void gemm2_kernel(
    const unsigned short* __restrict__ H, const unsigned short* __restrict__ w2t,
    const int* __restrict__ cnt, const int* __restrict__ ilist,
    const float* __restrict__ wlist, float* __restrict__ P) {
  int flat = blockIdx.x;       // 1024 blocks
  int e = flat & 7;
  int widx = flat >> 3;        // 0..127
  int ne = cnt[e];
  int art = (ne + 255) >> 8;
  if (widx >= (art << 2)) return;
  int nt = widx & 3;           // nt-fast: 4 nt share each contiguous H window
  int rt = widx >> 2;
  int r0 = rt * 256;
  int hbase = 0;
#pragma unroll
  for (int j = 0; j < E_NUM; ++j) hbase += (j < e) ? cnt[j] : 0;
  __shared__ __align__(16) unsigned short As[3 * 8192];
  __shared__ __align__(16) unsigned short Bs[3 * 8192];
  __shared__ int toks[256];
  __shared__ float wts[256];
  int tid = threadIdx.x, lane = tid & 63, w = tid >> 6;
  if (tid < 256) {
    int idx = e * T_TOK + min(r0 + tid, ne - 1);
    toks[tid] = ilist[idx];
    wts[tid] = wlist[idx];
  }
  __syncthreads();
  const unsigned short* bpanel = w2t + ((size_t)e * D_DIM + nt * 256) * F_DIM;
  int sr0 = tid >> 2, sr1 = sr0 + 128;
  int ch0 = (((tid & 3) ^ ((sr0 >> 1) & 3)) * 8);
  int ch1 = (((tid & 3) ^ ((sr1 >> 1) & 3)) * 8);
  const unsigned short* ap0 = H + (size_t)(hbase + min(r0 + sr0, ne - 1)) * F_DIM + ch0;
  const unsigned short* ap1 = H + (size_t)(hbase + min(r0 + sr1, ne - 1)) * F_DIM + ch1;
  const unsigned short* bp0 = bpanel + (size_t)sr0 * F_DIM + ch0;
  const unsigned short* bp1 = bpanel + (size_t)sr1 * F_DIM + ch1;
  int d0 = (sr0 * 32) + (tid & 3) * 8;
  int d1 = d0 + 4096;
  int wr = w >> 2, wc = w & 3;
  int lr = lane & 15, lc = lane >> 4;
  int aoff[8], boff[4];
#pragma unroll
  for (int m = 0; m < 8; ++m) {
    int row = wr * 128 + m * 16 + lr;
    aoff[m] = row * 32 + ((lc ^ ((row >> 1) & 3)) * 8);
  }
#pragma unroll
  for (int n = 0; n < 4; ++n) {
    int row = wc * 64 + n * 16 + lr;
    boff[n] = row * 32 + ((lc ^ ((row >> 1) & 3)) * 8);
  }
  f32x4 acc[8][4] = {};
  async16(ap0, &As[d0]); async16(ap1, &As[d1]);
  async16(bp0, &Bs[d0]); async16(bp1, &Bs[d1]);
  async16(ap0 + 32, &As[8192 + d0]); async16(ap1 + 32, &As[8192 + d1]);
  async16(bp0 + 32, &Bs[8192 + d0]); async16(bp1 + 32, &Bs[8192 + d1]);

#define G2_STEP(T_, BUF_, VMC_, DOST_)                                          \
  {                                                                             \
    asm volatile("s_waitcnt vmcnt(" VMC_ ")" ::: "memory");                     \
    __builtin_amdgcn_s_barrier();                                               \
    const unsigned short* Ab = &As[(BUF_) * 8192];                              \
    const unsigned short* Bb = &Bs[(BUF_) * 8192];                              \
    s16x8 a[8], b[4];                                                           \
    if (DOST_) {                                                                \
      int nk = ((T_) + 2) * 32;                                                 \
      async16(ap0 + nk, &As[(((BUF_) + 2) % 3) * 8192 + d0]);                   \
      async16(ap1 + nk, &As[(((BUF_) + 2) % 3) * 8192 + d1]);                   \
    }                                                                           \
    _Pragma("unroll") for (int m = 0; m < 4; ++m)                               \
        a[m] = *(const s16x8*)(Ab + aoff[m]);                                   \
    _Pragma("unroll") for (int n = 0; n < 4; ++n)                               \
        b[n] = *(const s16x8*)(Bb + boff[n]);                                   \
    __builtin_amdgcn_s_setprio(1);                                              \
    _Pragma("unroll") for (int m = 0; m < 4; ++m)                               \
        _Pragma("unroll") for (int n = 0; n < 4; ++n)                           \
            acc[m][n] = __builtin_amdgcn_mfma_f32_16x16x32_bf16(                \
                a[m], b[n], acc[m][n], 0, 0, 0);                                \
    __builtin_amdgcn_s_setprio(0);                                              \
    if (DOST_) {                                                                \
      int nk = ((T_) + 2) * 32;                                                 \
      async16(bp0 + nk, &Bs[(((BUF_) + 2) % 3) * 8192 + d0]);                   \
      async16(bp1 + nk, &Bs[(((BUF_) + 2) % 3) * 8192 + d1]);                   \
    }                                                                           \
    _Pragma("unroll") for (int m = 4; m < 8; ++m)                               \
        a[m] = *(const s16x8*)(Ab + aoff[m]);                                   \
    __builtin_amdgcn_s_setprio(1);                                              \
    _Pragma("unroll") for (int m = 4; m < 8; ++m)                               \
        _Pragma("unroll") for (int n = 0; n < 4; ++n)                           \
            acc[m][n] = __builtin_amdgcn_mfma_f32_16x16x32_bf16(                \
                a[m], b[n], acc[m][n], 0, 0, 0);                                \
    __builtin_amdgcn_s_setprio(0);                                              \
  }

  for (int tb = 0; tb < 126; tb += 3) {
    G2_STEP(tb, 0, "4", 1)
    G2_STEP(tb + 1, 1, "4", 1)
    G2_STEP(tb + 2, 2, "4", 1)
  }
  G2_STEP(126, 0, "4", 0)
  G2_STEP(127, 1, "0", 0)
#undef G2_STEP

  int g4 = lane >> 4, cl = lane & 15;
#pragma unroll
  for (int m = 0; m < 8; ++m) {
#pragma unroll
    for (int j = 0; j < 4; ++j) {
      int rloc = wr * 128 + m * 16 + g4 * 4 + j;
      if (r0 + rloc < ne) {
        int slot = toks[rloc];           // unique writer per slot: plain stores
        float ww = wts[rloc];
        float* pp = P + (size_t)slot * D_DIM + nt * 256 + wc * 64 + cl;
#pragma unroll
        for (int n = 0; n < 4; ++n)
          pp[n * 16] = ww * acc[m][n][j];
      }
    }
  }
}

// ---- combine: out[t] = P[2t] + P[2t+1] (float4, 2M elements) ----
__global__ __launch_bounds__(256) void combine_kernel(
    const float* __restrict__ P, float* __restrict__ out) {
  int i = blockIdx.x * 256 + threadIdx.x;   // float4 index base
#pragma unroll
  for (int k = 0; k < 4; ++k) {
    int idx = i + k * 524288;               // 2048 blocks * 256 thr = 524288
    int t = idx >> 8, c = idx & 255;
    float4 a = ((const float4*)P)[(size_t)(t * 2) * 256 + c];
    float4 b = ((const float4*)P)[(size_t)(t * 2 + 1) * 256 + c];
    float4 o;
    o.x = a.x + b.x; o.y = a.y + b.y; o.z = a.z + b.z; o.w = a.w + b.w;
    ((float4*)out)[idx] = o;
  }
}

extern "C" void kernel_launch(void* const* d_in, const int* in_sizes, int n_in,
                              void* d_out, int out_size, void* d_ws, size_t ws_size,
                              hipStream_t stream) {
  const float* hs = (const float*)d_in[0];
  const float* nw = (const float*)d_in[1];
  const float* gw = (const float*)d_in[2];
  const float* w1 = (const float*)d_in[3];
  const float* w3 = (const float*)d_in[4];
  const float* w2 = (const float*)d_in[5];
  float* out = (float*)d_out;
  float* logits_out = out + (size_t)T_TOK * D_DIM;

  char* ws = (char*)d_ws;
  unsigned short* xb   = (unsigned short*)(ws);                 // 16 MiB bf16 x
  unsigned short* w13t = (unsigned short*)(ws + 16777216ull);   // 128 MiB [E][8192][D]
  unsigned short* w2t  = (unsigned short*)(ws + 150994944ull);  // 64 MiB [E][D][F]
  unsigned short* H    = (unsigned short*)(ws + 218103808ull);  // 128 MiB compacted [2T][F]
  float* P = (float*)(ws + 16777216ull);  // 64 MiB [2T][D] f32 — aliases dead w13t
  int*   ilist = (int*)(ws + 352321536ull);                     // [E][T] int
  float* wlist = (float*)(ws + 352583680ull);                   // [E][T] f32
  int*   cnt   = (int*)(ws + 352845824ull);                     // [E] int

  hipMemsetAsync(cnt, 0, E_NUM * sizeof(int), stream);
  prepass_kernel<<<16384 + T_TOK, 256, 0, stream>>>(
      hs, nw, gw, w1, w3, xb, w13t, logits_out, cnt, ilist, wlist);
  gemm1_kernel<<<E_NUM * 32 * 32, 512, 0, stream>>>(xb, w13t, H, cnt, ilist, w2, w2t);
  gemm2_kernel<<<E_NUM * 32 * 4, 512, 0, stream>>>(H, w2t, cnt, ilist, wlist, P);
  combine_kernel<<<2048, 256, 0, stream>>>(P, out);
}

// Round 17
// 831.925 us; speedup vs baseline: 1.0036x; 1.0036x over previous
//
#include <hip/hip_runtime.h>
#include <hip/hip_bf16.h>

#define T_TOK 8192
#define D_DIM 1024
#define F_DIM 4096
#define E_NUM 8

typedef short s16x8 __attribute__((ext_vector_type(8)));
typedef float f32x4 __attribute__((ext_vector_type(4)));
typedef unsigned short u16x8 __attribute__((ext_vector_type(8)));

__device__ __forceinline__ unsigned short f2bf(float f) {
  union { float f; unsigned int u; } v; v.f = f;
  unsigned int u = v.u;
  return (unsigned short)((u + 0x7FFFu + ((u >> 16) & 1u)) >> 16);  // RNE
}

__device__ __forceinline__ void async16(const void* g, void* l) {
  __builtin_amdgcn_global_load_lds((const __attribute__((address_space(1))) void*)g,
                                   (__attribute__((address_space(3))) void*)l, 16, 0, 0);
}

// ---- fused pre-pass: blocks 0..24575 = weight transpose; 24576.. = RMSNorm+router ----
__global__ __launch_bounds__(256) void prepass_kernel(
    const float* __restrict__ hs, const float* __restrict__ nw,
    const float* __restrict__ gw, const float* __restrict__ w1,
    const float* __restrict__ w3, const float* __restrict__ w2,
    unsigned short* __restrict__ xb, unsigned short* __restrict__ w13t,
    unsigned short* __restrict__ w2t, float* __restrict__ logits_out,
    int* __restrict__ cnt, int* __restrict__ ilist, float* __restrict__ wlist) {
  __shared__ unsigned short tileS[64][72];
  __shared__ float red[4];
  __shared__ float pl[4][8];
  int bx = blockIdx.x;
  int tid = threadIdx.x;
  if (bx < 24576) {
    int tensor = bx >> 13;
    int e = (bx >> 10) & 7;
    int tl = bx & 1023;
    const float* src; int C, tr, tc;
    if (tensor == 0) {
      src = w1 + (size_t)e * D_DIM * F_DIM; C = F_DIM; tr = tl >> 6; tc = tl & 63;
    } else if (tensor == 1) {
      src = w3 + (size_t)e * D_DIM * F_DIM; C = F_DIM; tr = tl >> 6; tc = tl & 63;
    } else {
      src = w2 + (size_t)e * F_DIM * D_DIM; C = D_DIM; tr = tl >> 4; tc = tl & 15;
    }
    int r0 = tr * 64, c0 = tc * 64;
    int rr = tid >> 4, ccb = (tid & 15) * 4;
#pragma unroll
    for (int i = 0; i < 4; ++i) {
      int r = rr + i * 16;
      float4 v = *(const float4*)(src + (size_t)(r0 + r) * C + c0 + ccb);
      tileS[ccb + 0][r] = f2bf(v.x);
      tileS[ccb + 1][r] = f2bf(v.y);
      tileS[ccb + 2][r] = f2bf(v.z);
      tileS[ccb + 3][r] = f2bf(v.w);
    }
    __syncthreads();
    int row = tid >> 2, col = (tid & 3) * 16;
    unsigned short* dp;
    if (tensor < 2) {
      int f = c0 + row;
      int prow = ((f >> 5) * 64) + (f & 31) + (tensor == 1 ? 32 : 0);
      dp = w13t + ((size_t)e * 8192 + prow) * D_DIM + r0 + col;
    } else {
      dp = w2t + ((size_t)e * D_DIM + c0 + row) * F_DIM + r0 + col;
    }
    u16x8 v0, v1;
#pragma unroll
    for (int j = 0; j < 8; ++j) { v0[j] = tileS[row][col + j]; v1[j] = tileS[row][col + 8 + j]; }
    *(u16x8*)dp = v0;
    *(u16x8*)(dp + 8) = v1;
  } else {
    int t = bx - 24576;
    int lane = tid & 63, wid = tid >> 6;
    float4 v = ((const float4*)(hs + (size_t)t * D_DIM))[tid];
    float ss = v.x * v.x + v.y * v.y + v.z * v.z + v.w * v.w;
#pragma unroll
    for (int o = 32; o > 0; o >>= 1) ss += __shfl_xor(ss, o);
    if (lane == 0) red[wid] = ss;
    __syncthreads();
    float ms = (red[0] + red[1] + red[2] + red[3]) * (1.0f / 1024.0f);
    float rs = rsqrtf(ms + 1e-6f);
    float4 wv = ((const float4*)nw)[tid];
    float x0 = v.x * rs * wv.x, x1 = v.y * rs * wv.y;
    float x2 = v.z * rs * wv.z, x3 = v.w * rs * wv.w;
    ((ushort4*)(xb + (size_t)t * D_DIM))[tid] =
        make_ushort4(f2bf(x0), f2bf(x1), f2bf(x2), f2bf(x3));
    float p[8];
#pragma unroll
    for (int e = 0; e < 8; ++e) {
      float4 g = ((const float4*)(gw + (size_t)e * D_DIM))[tid];
      p[e] = x0 * g.x + x1 * g.y + x2 * g.z + x3 * g.w;
    }
#pragma unroll
    for (int e = 0; e < 8; ++e) {
#pragma unroll
      for (int o = 32; o > 0; o >>= 1) p[e] += __shfl_xor(p[e], o);
    }
    if (lane == 0) {
#pragma unroll
      for (int e = 0; e < 8; ++e) pl[wid][e] = p[e];
    }
    __syncthreads();
    if (tid == 0) {
      float l[8];
#pragma unroll
      for (int e = 0; e < 8; ++e) {
        l[e] = pl[0][e] + pl[1][e] + pl[2][e] + pl[3][e];
        logits_out[(size_t)t * 8 + e] = l[e];
      }
      int i0 = 0; float b0 = l[0];
#pragma unroll
      for (int e = 1; e < 8; ++e) if (l[e] > b0) { b0 = l[e]; i0 = e; }
      int i1 = (i0 == 0) ? 1 : 0; float b1 = l[i1];
#pragma unroll
      for (int e = 0; e < 8; ++e) if (e != i0 && l[e] > b1) { b1 = l[e]; i1 = e; }
      float wa = 1.0f / (1.0f + __expf(b1 - b0));
      float wb = 1.0f / (1.0f + __expf(b0 - b1));
      int p0 = atomicAdd(&cnt[i0], 1);
      ilist[i0 * T_TOK + p0] = t * 2;     wlist[i0 * T_TOK + p0] = wa;
      int p1 = atomicAdd(&cnt[i1], 1);
      ilist[i1 * T_TOK + p1] = t * 2 + 1; wlist[i1 * T_TOK + p1] = wb;
    }
  }
}

// ---- GEMM1: H = silu(Xe@W1e)*(Xe@W3e). 256x256 block, compacted-H output ----
__global__ __launch_bounds__(512, 2) void gemm1_kernel(
    const unsigned short* __restrict__ xb, const unsigned short* __restrict__ w13t,
    unsigned short* __restrict__ H, const int* __restrict__ cnt,
    const int* __restrict__ ilist) {
  int flat = blockIdx.x;       // 8192 blocks
  int e = flat & 7;            // expert == XCD
  int widx = flat >> 3;        // 0..1023
  int ne = cnt[e];
  int art = (ne + 255) >> 8;   // active row-tiles (<=32)
  if (widx >= (art << 5)) return;
  int rt = widx % art;         // rt-fast: rt blocks share each B-slice
  int ft = widx / art;         // 0..31
  int r0 = rt * 256;
  int hbase = 0;               // compacted-H base = prefix sum of cnt
#pragma unroll
  for (int j = 0; j < E_NUM; ++j) hbase += (j < e) ? cnt[j] : 0;
  __shared__ __align__(16) unsigned short As[3 * 8192];  // [3][256][32]
  __shared__ __align__(16) unsigned short Bs[3 * 8192];
  __shared__ int toks[256];
  int tid = threadIdx.x, lane = tid & 63, w = tid >> 6;
  if (tid < 256) toks[tid] = ilist[e * T_TOK + min(r0 + tid, ne - 1)];
  __syncthreads();
  const unsigned short* bpanel = w13t + ((size_t)e * 8192 + ft * 256) * D_DIM;
  int sr0 = tid >> 2, sr1 = sr0 + 128;
  int ch0 = (((tid & 3) ^ ((sr0 >> 1) & 3)) * 8);
  int ch1 = (((tid & 3) ^ ((sr1 >> 1) & 3)) * 8);
  const unsigned short* ap0 = xb + (size_t)(toks[sr0] >> 1) * D_DIM + ch0;
  const unsigned short* ap1 = xb + (size_t)(toks[sr1] >> 1) * D_DIM + ch1;
  const unsigned short* bp0 = bpanel + (size_t)sr0 * D_DIM + ch0;
  const unsigned short* bp1 = bpanel + (size_t)sr1 * D_DIM + ch1;
  int d0 = (sr0 * 32) + (tid & 3) * 8;
  int d1 = d0 + 4096;
  int wr = w >> 2, wc = w & 3;           // 2 x 4 wave grid
  int lr = lane & 15, lc = lane >> 4;
  int aoff[8], boff[4];
#pragma unroll
  for (int m = 0; m < 8; ++m) {
    int row = wr * 128 + m * 16 + lr;
    aoff[m] = row * 32 + ((lc ^ ((row >> 1) & 3)) * 8);
  }
#pragma unroll
  for (int n = 0; n < 4; ++n) {
    int row = wc * 64 + n * 16 + lr;
    boff[n] = row * 32 + ((lc ^ ((row >> 1) & 3)) * 8);
  }
  f32x4 acc[8][4] = {};
  async16(ap0, &As[d0]); async16(ap1, &As[d1]);
  async16(bp0, &Bs[d0]); async16(bp1, &Bs[d1]);
  async16(ap0 + 32, &As[8192 + d0]); async16(ap1 + 32, &As[8192 + d1]);
  async16(bp0 + 32, &Bs[8192 + d0]); async16(bp1 + 32, &Bs[8192 + d1]);

#define G1_STEP(T_, BUF_, VMC_, DOST_)                                          \
  {                                                                             \
    asm volatile("s_waitcnt vmcnt(" VMC_ ")" ::: "memory");                     \
    __builtin_amdgcn_s_barrier();                                               \
    const unsigned short* Ab = &As[(BUF_) * 8192];                              \
    const unsigned short* Bb = &Bs[(BUF_) * 8192];                              \
    s16x8 a[8], b[4];                                                           \
    if (DOST_) { /* phase 1 stage: A of t+2 */                                  \
      int nk = ((T_) + 2) * 32;                                                 \
      async16(ap0 + nk, &As[(((BUF_) + 2) % 3) * 8192 + d0]);                   \
      async16(ap1 + nk, &As[(((BUF_) + 2) % 3) * 8192 + d1]);                   \
    }                                                                           \
    _Pragma("unroll") for (int m = 0; m < 4; ++m)                               \
        a[m] = *(const s16x8*)(Ab + aoff[m]);                                   \
    _Pragma("unroll") for (int n = 0; n < 4; ++n)                               \
        b[n] = *(const s16x8*)(Bb + boff[n]);                                   \
    __builtin_amdgcn_s_setprio(1);                                              \
    _Pragma("unroll") for (int m = 0; m < 4; ++m)                               \
        _Pragma("unroll") for (int n = 0; n < 4; ++n)                           \
            acc[m][n] = __builtin_amdgcn_mfma_f32_16x16x32_bf16(                \
                a[m], b[n], acc[m][n], 0, 0, 0);                                \
    __builtin_amdgcn_s_setprio(0);                                              \
    if (DOST_) { /* phase 2 stage: B of t+2 */                                  \
      int nk = ((T_) + 2) * 32;                                                 \
      async16(bp0 + nk, &Bs[(((BUF_) + 2) % 3) * 8192 + d0]);                   \
      async16(bp1 + nk, &Bs[(((BUF_) + 2) % 3) * 8192 + d1]);                   \
    }                                                                           \
    _Pragma("unroll") for (int m = 4; m < 8; ++m)                               \
        a[m] = *(const s16x8*)(Ab + aoff[m]);                                   \
    __builtin_amdgcn_s_setprio(1);                                              \
    _Pragma("unroll") for (int m = 4; m < 8; ++m)                               \
        _Pragma("unroll") for (int n = 0; n < 4; ++n)                           \
            acc[m][n] = __builtin_amdgcn_mfma_f32_16x16x32_bf16(                \
                a[m], b[n], acc[m][n], 0, 0, 0);                                \
    __builtin_amdgcn_s_setprio(0);                                              \
  }

  for (int tb = 0; tb < 30; tb += 3) {
    G1_STEP(tb, 0, "4", 1)
    G1_STEP(tb + 1, 1, "4", 1)
    G1_STEP(tb + 2, 2, "4", 1)
  }
  G1_STEP(30, 0, "4", 0)
  G1_STEP(31, 1, "0", 0)
#undef G1_STEP

  int g4 = lane >> 4, cl = lane & 15;
  int fbase = (4 * ft + wc) * 32;   // 32 f-cols per wave (w1 n=0,1 ; w3 n=2,3)
#pragma unroll
  for (int m = 0; m < 8; ++m) {
#pragma unroll
    for (int j = 0; j < 4; ++j) {
      int rloc = wr * 128 + m * 16 + g4 * 4 + j;
      if (r0 + rloc < ne) {
        unsigned short* hp = H + (size_t)(hbase + r0 + rloc) * F_DIM + fbase + cl;
#pragma unroll
        for (int n = 0; n < 2; ++n) {
          float c1 = acc[m][n][j], c3 = acc[m][n + 2][j];
          float h = c1 / (1.0f + __expf(-c1)) * c3;
          hp[n * 16] = f2bf(h);
        }
      }
    }
  }
}

// ---- GEMM2: P[slot] = w * (He @ W2e). 128x256 block, 4 waves, 2 blocks/CU ----
__global__ __launch_bounds__(256, 2) void gemm2_kernel(
    const unsigned short* __restrict__ H, const unsigned short* __restrict__ w2t,
    const int* __restrict__ cnt, const int* __restrict__ ilist,
    const float* __restrict__ wlist, float* __restrict__ P) {
  int flat = blockIdx.x;       // 2048 blocks
  int e = flat & 7;
  int widx = flat >> 3;        // 0..255
  int ne = cnt[e];
  int art = (ne + 127) >> 7;   // 128-row tiles (<=64)
  if (widx >= (art << 2)) return;
  int nt = widx & 3;           // nt-fast: 4 nt share each contiguous H window
  int rt = widx >> 2;
  int r0 = rt * 128;
  int hbase = 0;
#pragma unroll
  for (int j = 0; j < E_NUM; ++j) hbase += (j < e) ? cnt[j] : 0;
  __shared__ __align__(16) unsigned short As[3 * 4096];  // [3][128][32]
  __shared__ __align__(16) unsigned short Bs[3 * 8192];  // [3][256][32]
  __shared__ int toks[128];
  __shared__ float wts[128];
  int tid = threadIdx.x, lane = tid & 63, w = tid >> 6;
  if (tid < 128) {
    int idx = e * T_TOK + min(r0 + tid, ne - 1);
    toks[tid] = ilist[idx];
    wts[tid] = wlist[idx];
  }
  __syncthreads();
  const unsigned short* bpanel = w2t + ((size_t)e * D_DIM + nt * 256) * F_DIM;
  // A staging: thread covers rows tid>>2 and 64+(tid>>2), chunk tid&3
  int ar0 = tid >> 2, ar1 = ar0 + 64;
  int ca0 = (((tid & 3) ^ ((ar0 >> 1) & 3)) * 8);
  int ca1 = (((tid & 3) ^ ((ar1 >> 1) & 3)) * 8);
  const unsigned short* ap0 = H + (size_t)(hbase + min(r0 + ar0, ne - 1)) * F_DIM + ca0;
  const unsigned short* ap1 = H + (size_t)(hbase + min(r0 + ar1, ne - 1)) * F_DIM + ca1;
  int da0 = tid * 8;            // = ar0*32 + (tid&3)*8 (linear)
  int da1 = 2048 + tid * 8;
  // B staging: rows tid>>2 + {0,64,128,192}
  int br0 = tid >> 2, br1 = br0 + 64, br2 = br0 + 128, br3 = br0 + 192;
  int cb0 = (((tid & 3) ^ ((br0 >> 1) & 3)) * 8);
  int cb1 = (((tid & 3) ^ ((br1 >> 1) & 3)) * 8);
  int cb2 = (((tid & 3) ^ ((br2 >> 1) & 3)) * 8);
  int cb3 = (((tid & 3) ^ ((br3 >> 1) & 3)) * 8);
  const unsigned short* bp0 = bpanel + (size_t)br0 * F_DIM + cb0;
  const unsigned short* bp1 = bpanel + (size_t)br1 * F_DIM + cb1;
  const unsigned short* bp2 = bpanel + (size_t)br2 * F_DIM + cb2;
  const unsigned short* bp3 = bpanel + (size_t)br3 * F_DIM + cb3;
  int db0 = tid * 8, db1 = 2048 + tid * 8, db2 = 4096 + tid * 8, db3 = 6144 + tid * 8;
  int wr = w >> 1, wc = w & 1;  // 2x2 wave grid, wave tile 64x128
  int lr = lane & 15, lc = lane >> 4;
  int aoff[4], boff[8];
#pragma unroll
  for (int m = 0; m < 4; ++m) {
    int row = wr * 64 + m * 16 + lr;
    aoff[m] = row * 32 + ((lc ^ ((row >> 1) & 3)) * 8);
  }
#pragma unroll
  for (int n = 0; n < 8; ++n) {
    int row = wc * 128 + n * 16 + lr;
    boff[n] = row * 32 + ((lc ^ ((row >> 1) & 3)) * 8);
  }
  f32x4 acc[4][8] = {};
  // prologue: stage tiles 0,1 (6 loads/thread each); keep tile1 in flight
  async16(ap0, &As[da0]); async16(ap1, &As[da1]);
  async16(bp0, &Bs[db0]); async16(bp1, &Bs[db1]);
  async16(bp2, &Bs[db2]); async16(bp3, &Bs[db3]);
  async16(ap0 + 32, &As[4096 + da0]); async16(ap1 + 32, &As[4096 + da1]);
  async16(bp0 + 32, &Bs[8192 + db0]); async16(bp1 + 32, &Bs[8192 + db1]);
  async16(bp2 + 32, &Bs[8192 + db2]); async16(bp3 + 32, &Bs[8192 + db3]);
  asm volatile("s_waitcnt vmcnt(6)" ::: "memory");
  __builtin_amdgcn_s_barrier();

#define G2_STEP(T_, BUF_, VMC_, DOST_)                                          \
  {                                                                             \
    const unsigned short* Ab = &As[(BUF_) * 4096];                              \
    const unsigned short* Bb = &Bs[(BUF_) * 8192];                              \
    s16x8 a[4], b[8];                                                           \
    if (DOST_) {                                                                \
      int nk = ((T_) + 2) * 32;                                                 \
      int nb = ((BUF_) + 2) % 3;                                                \
      async16(ap0 + nk, &As[nb * 4096 + da0]);                                  \
      async16(ap1 + nk, &As[nb * 4096 + da1]);                                  \
      async16(bp0 + nk, &Bs[nb * 8192 + db0]);                                  \
      async16(bp1 + nk, &Bs[nb * 8192 + db1]);                                  \
      async16(bp2 + nk, &Bs[nb * 8192 + db2]);                                  \
      async16(bp3 + nk, &Bs[nb * 8192 + db3]);                                  \
    }                                                                           \
    _Pragma("unroll") for (int m = 0; m < 4; ++m)                               \
        a[m] = *(const s16x8*)(Ab + aoff[m]);                                   \
    _Pragma("unroll") for (int n = 0; n < 8; ++n)                               \
        b[n] = *(const s16x8*)(Bb + boff[n]);                                   \
    __builtin_amdgcn_s_setprio(1);                                              \
    _Pragma("unroll") for (int m = 0; m < 4; ++m)                               \
        _Pragma("unroll") for (int n = 0; n < 8; ++n)                           \
            acc[m][n] = __builtin_amdgcn_mfma_f32_16x16x32_bf16(                \
                a[m], b[n], acc[m][n], 0, 0, 0);                                \
    __builtin_amdgcn_s_setprio(0);                                              \
    asm volatile("s_waitcnt vmcnt(" VMC_ ")" ::: "memory");                     \
    __builtin_amdgcn_s_barrier();                                               \
  }

  for (int tb = 0; tb < 126; tb += 3) {
    G2_STEP(tb, 0, "6", 1)
    G2_STEP(tb + 1, 1, "6", 1)
    G2_STEP(tb + 2, 2, "6", 1)
  }
  G2_STEP(126, 0, "0", 0)
  G2_STEP(127, 1, "0", 0)
#undef G2_STEP

  int g4 = lane >> 4, cl = lane & 15;
#pragma unroll
  for (int m = 0; m < 4; ++m) {
#pragma unroll
    for (int j = 0; j < 4; ++j) {
      int rloc = wr * 64 + m * 16 + g4 * 4 + j;
      if (r0 + rloc < ne) {
        int slot = toks[rloc];           // unique writer per slot: plain stores
        float ww = wts[rloc];
        float* pp = P + (size_t)slot * D_DIM + nt * 256 + wc * 128 + cl;
#pragma unroll
        for (int n = 0; n < 8; ++n)
          pp[n * 16] = ww * acc[m][n][j];
      }
    }
  }
}

// ---- combine: out[t] = P[2t] + P[2t+1] (float4, 2M elements) ----
__global__ __launch_bounds__(256) void combine_kernel(
    const float* __restrict__ P, float* __restrict__ out) {
  int i = blockIdx.x * 256 + threadIdx.x;   // float4 index base
#pragma unroll
  for (int k = 0; k < 4; ++k) {
    int idx = i + k * 524288;               // 2048 blocks * 256 thr = 524288
    int t = idx >> 8, c = idx & 255;
    float4 a = ((const float4*)P)[(size_t)(t * 2) * 256 + c];
    float4 b = ((const float4*)P)[(size_t)(t * 2 + 1) * 256 + c];
    float4 o;
    o.x = a.x + b.x; o.y = a.y + b.y; o.z = a.z + b.z; o.w = a.w + b.w;
    ((float4*)out)[idx] = o;
  }
}

extern "C" void kernel_launch(void* const* d_in, const int* in_sizes, int n_in,
                              void* d_out, int out_size, void* d_ws, size_t ws_size,
                              hipStream_t stream) {
  const float* hs = (const float*)d_in[0];
  const float* nw = (const float*)d_in[1];
  const float* gw = (const float*)d_in[2];
  const float* w1 = (const float*)d_in[3];
  const float* w3 = (const float*)d_in[4];
  const float* w2 = (const float*)d_in[5];
  float* out = (float*)d_out;
  float* logits_out = out + (size_t)T_TOK * D_DIM;

  char* ws = (char*)d_ws;
  unsigned short* xb   = (unsigned short*)(ws);                 // 16 MiB bf16 x
  unsigned short* w13t = (unsigned short*)(ws + 16777216ull);   // 128 MiB [E][8192][D]
  unsigned short* w2t  = (unsigned short*)(ws + 150994944ull);  // 64 MiB [E][D][F]
  unsigned short* H    = (unsigned short*)(ws + 218103808ull);  // 128 MiB compacted [2T][F]
  float* P = (float*)(ws + 16777216ull);  // 64 MiB [2T][D] f32 — aliases dead w13t
  int*   ilist = (int*)(ws + 352321536ull);                     // [E][T] int
  float* wlist = (float*)(ws + 352583680ull);                   // [E][T] f32
  int*   cnt   = (int*)(ws + 352845824ull);                     // [E] int

  hipMemsetAsync(cnt, 0, E_NUM * sizeof(int), stream);
  prepass_kernel<<<24576 + T_TOK, 256, 0, stream>>>(
      hs, nw, gw, w1, w3, w2, xb, w13t, w2t, logits_out, cnt, ilist, wlist);
  gemm1_kernel<<<E_NUM * 32 * 32, 512, 0, stream>>>(xb, w13t, H, cnt, ilist);
  gemm2_kernel<<<E_NUM * 64 * 4, 256, 0, stream>>>(H, w2t, cnt, ilist, wlist, P);
  combine_kernel<<<2048, 256, 0, stream>>>(P, out);
}

// Round 18
// 816.796 us; speedup vs baseline: 1.0222x; 1.0185x over previous
//
#include <hip/hip_runtime.h>
#include <hip/hip_bf16.h>

#define T_TOK 8192
#define D_DIM 1024
#define F_DIM 4096
#define E_NUM 8

typedef short s16x8 __attribute__((ext_vector_type(8)));
typedef float f32x4 __attribute__((ext_vector_type(4)));
typedef unsigned short u16x8 __attribute__((ext_vector_type(8)));

__device__ __forceinline__ unsigned short f2bf(float f) {
  union { float f; unsigned int u; } v; v.f = f;
  unsigned int u = v.u;
  return (unsigned short)((u + 0x7FFFu + ((u >> 16) & 1u)) >> 16);  // RNE
}

__device__ __forceinline__ void async16(const void* g, void* l) {
  __builtin_amdgcn_global_load_lds((const __attribute__((address_space(1))) void*)g,
                                   (__attribute__((address_space(3))) void*)l, 16, 0, 0);
}

// ---- fused pre-pass: blocks 0..24575 = weight transpose; 24576.. = RMSNorm+router ----
// Transpose: 4x4 in-register sub-tile transpose -> 8-byte LDS writes (stride 68).
__global__ __launch_bounds__(256) void prepass_kernel(
    const float* __restrict__ hs, const float* __restrict__ nw,
    const float* __restrict__ gw, const float* __restrict__ w1,
    const float* __restrict__ w3, const float* __restrict__ w2,
    unsigned short* __restrict__ xb, unsigned short* __restrict__ w13t,
    unsigned short* __restrict__ w2t, float* __restrict__ logits_out,
    int* __restrict__ cnt, int* __restrict__ ilist, float* __restrict__ wlist) {
  __shared__ unsigned short tileS[64 * 68];  // [c][r], row stride 68 (8B-aligned)
  __shared__ float red[4];
  __shared__ float pl[4][8];
  int bx = blockIdx.x;
  int tid = threadIdx.x;
  if (bx < 24576) {
    int tensor = bx >> 13;
    int e = (bx >> 10) & 7;
    int tl = bx & 1023;
    const float* src; int C, tr, tc;
    if (tensor == 0) {
      src = w1 + (size_t)e * D_DIM * F_DIM; C = F_DIM; tr = tl >> 6; tc = tl & 63;
    } else if (tensor == 1) {
      src = w3 + (size_t)e * D_DIM * F_DIM; C = F_DIM; tr = tl >> 6; tc = tl & 63;
    } else {
      src = w2 + (size_t)e * F_DIM * D_DIM; C = D_DIM; tr = tl >> 4; tc = tl & 15;
    }
    int r0 = tr * 64, c0 = tc * 64;
    int rr = (tid >> 4) * 4, cc = (tid & 15) * 4;
    const float* sp = src + (size_t)(r0 + rr) * C + c0 + cc;
    float4 v0 = *(const float4*)(sp);
    float4 v1 = *(const float4*)(sp + C);
    float4 v2 = *(const float4*)(sp + 2 * (size_t)C);
    float4 v3 = *(const float4*)(sp + 3 * (size_t)C);
    ushort4 o0 = make_ushort4(f2bf(v0.x), f2bf(v1.x), f2bf(v2.x), f2bf(v3.x));
    ushort4 o1 = make_ushort4(f2bf(v0.y), f2bf(v1.y), f2bf(v2.y), f2bf(v3.y));
    ushort4 o2 = make_ushort4(f2bf(v0.z), f2bf(v1.z), f2bf(v2.z), f2bf(v3.z));
    ushort4 o3 = make_ushort4(f2bf(v0.w), f2bf(v1.w), f2bf(v2.w), f2bf(v3.w));
    *(ushort4*)&tileS[(cc + 0) * 68 + rr] = o0;
    *(ushort4*)&tileS[(cc + 1) * 68 + rr] = o1;
    *(ushort4*)&tileS[(cc + 2) * 68 + rr] = o2;
    *(ushort4*)&tileS[(cc + 3) * 68 + rr] = o3;
    __syncthreads();
    int row = tid >> 2, col = (tid & 3) * 16;
    unsigned short* dp;
    if (tensor < 2) {
      int f = c0 + row;
      int prow = ((f >> 5) * 64) + (f & 31) + (tensor == 1 ? 32 : 0);
      dp = w13t + ((size_t)e * 8192 + prow) * D_DIM + r0 + col;
    } else {
      dp = w2t + ((size_t)e * D_DIM + c0 + row) * F_DIM + r0 + col;
    }
    u16x8 q0, q1;
#pragma unroll
    for (int j = 0; j < 8; ++j) {
      q0[j] = tileS[row * 68 + col + j];
      q1[j] = tileS[row * 68 + col + 8 + j];
    }
    *(u16x8*)dp = q0;
    *(u16x8*)(dp + 8) = q1;
  } else {
    int t = bx - 24576;
    int lane = tid & 63, wid = tid >> 6;
    float4 v = ((const float4*)(hs + (size_t)t * D_DIM))[tid];
    float ss = v.x * v.x + v.y * v.y + v.z * v.z + v.w * v.w;
#pragma unroll
    for (int o = 32; o > 0; o >>= 1) ss += __shfl_xor(ss, o);
    if (lane == 0) red[wid] = ss;
    __syncthreads();
    float ms = (red[0] + red[1] + red[2] + red[3]) * (1.0f / 1024.0f);
    float rs = rsqrtf(ms + 1e-6f);
    float4 wv = ((const float4*)nw)[tid];
    float x0 = v.x * rs * wv.x, x1 = v.y * rs * wv.y;
    float x2 = v.z * rs * wv.z, x3 = v.w * rs * wv.w;
    ((ushort4*)(xb + (size_t)t * D_DIM))[tid] =
        make_ushort4(f2bf(x0), f2bf(x1), f2bf(x2), f2bf(x3));
    float p[8];
#pragma unroll
    for (int e = 0; e < 8; ++e) {
      float4 g = ((const float4*)(gw + (size_t)e * D_DIM))[tid];
      p[e] = x0 * g.x + x1 * g.y + x2 * g.z + x3 * g.w;
    }
#pragma unroll
    for (int e = 0; e < 8; ++e) {
#pragma unroll
      for (int o = 32; o > 0; o >>= 1) p[e] += __shfl_xor(p[e], o);
    }
    if (lane == 0) {
#pragma unroll
      for (int e = 0; e < 8; ++e) pl[wid][e] = p[e];
    }
    __syncthreads();
    if (tid == 0) {
      float l[8];
#pragma unroll
      for (int e = 0; e < 8; ++e) {
        l[e] = pl[0][e] + pl[1][e] + pl[2][e] + pl[3][e];
        logits_out[(size_t)t * 8 + e] = l[e];
      }
      int i0 = 0; float b0 = l[0];
#pragma unroll
      for (int e = 1; e < 8; ++e) if (l[e] > b0) { b0 = l[e]; i0 = e; }
      int i1 = (i0 == 0) ? 1 : 0; float b1 = l[i1];
#pragma unroll
      for (int e = 0; e < 8; ++e) if (e != i0 && l[e] > b1) { b1 = l[e]; i1 = e; }
      float wa = 1.0f / (1.0f + __expf(b1 - b0));
      float wb = 1.0f / (1.0f + __expf(b0 - b1));
      int p0 = atomicAdd(&cnt[i0], 1);
      ilist[i0 * T_TOK + p0] = t * 2;     wlist[i0 * T_TOK + p0] = wa;
      int p1 = atomicAdd(&cnt[i1], 1);
      ilist[i1 * T_TOK + p1] = t * 2 + 1; wlist[i1 * T_TOK + p1] = wb;
    }
  }
}

// ---- GEMM1: H = silu(Xe@W1e)*(Xe@W3e). 256x256 block, compacted-H output ----
__global__ __launch_bounds__(512, 2) void gemm1_kernel(
    const unsigned short* __restrict__ xb, const unsigned short* __restrict__ w13t,
    unsigned short* __restrict__ H, const int* __restrict__ cnt,
    const int* __restrict__ ilist) {
  int flat = blockIdx.x;       // 8192 blocks
  int e = flat & 7;            // expert == XCD
  int widx = flat >> 3;        // 0..1023
  int ne = cnt[e];
  int art = (ne + 255) >> 8;   // active row-tiles (<=32)
  if (widx >= (art << 5)) return;
  int rt = widx % art;         // rt-fast: rt blocks share each B-slice
  int ft = widx / art;         // 0..31
  int r0 = rt * 256;
  int hbase = 0;               // compacted-H base = prefix sum of cnt
#pragma unroll
  for (int j = 0; j < E_NUM; ++j) hbase += (j < e) ? cnt[j] : 0;
  __shared__ __align__(16) unsigned short As[3 * 8192];  // [3][256][32]
  __shared__ __align__(16) unsigned short Bs[3 * 8192];
  __shared__ int toks[256];
  int tid = threadIdx.x, lane = tid & 63, w = tid >> 6;
  if (tid < 256) toks[tid] = ilist[e * T_TOK + min(r0 + tid, ne - 1)];
  __syncthreads();
  const unsigned short* bpanel = w13t + ((size_t)e * 8192 + ft * 256) * D_DIM;
  int sr0 = tid >> 2, sr1 = sr0 + 128;
  int ch0 = (((tid & 3) ^ ((sr0 >> 1) & 3)) * 8);
  int ch1 = (((tid & 3) ^ ((sr1 >> 1) & 3)) * 8);
  const unsigned short* ap0 = xb + (size_t)(toks[sr0] >> 1) * D_DIM + ch0;
  const unsigned short* ap1 = xb + (size_t)(toks[sr1] >> 1) * D_DIM + ch1;
  const unsigned short* bp0 = bpanel + (size_t)sr0 * D_DIM + ch0;
  const unsigned short* bp1 = bpanel + (size_t)sr1 * D_DIM + ch1;
  int d0 = (sr0 * 32) + (tid & 3) * 8;
  int d1 = d0 + 4096;
  int wr = w >> 2, wc = w & 3;           // 2 x 4 wave grid
  int lr = lane & 15, lc = lane >> 4;
  int aoff[8], boff[4];
#pragma unroll
  for (int m = 0; m < 8; ++m) {
    int row = wr * 128 + m * 16 + lr;
    aoff[m] = row * 32 + ((lc ^ ((row >> 1) & 3)) * 8);
  }
#pragma unroll
  for (int n = 0; n < 4; ++n) {
    int row = wc * 64 + n * 16 + lr;
    boff[n] = row * 32 + ((lc ^ ((row >> 1) & 3)) * 8);
  }
  f32x4 acc[8][4] = {};
  async16(ap0, &As[d0]); async16(ap1, &As[d1]);
  async16(bp0, &Bs[d0]); async16(bp1, &Bs[d1]);
  async16(ap0 + 32, &As[8192 + d0]); async16(ap1 + 32, &As[8192 + d1]);
  async16(bp0 + 32, &Bs[8192 + d0]); async16(bp1 + 32, &Bs[8192 + d1]);

#define G1_STEP(T_, BUF_, VMC_, DOST_)                                          \
  {                                                                             \
    asm volatile("s_waitcnt vmcnt(" VMC_ ")" ::: "memory");                     \
    __builtin_amdgcn_s_barrier();                                               \
    const unsigned short* Ab = &As[(BUF_) * 8192];                              \
    const unsigned short* Bb = &Bs[(BUF_) * 8192];                              \
    s16x8 a[8], b[4];                                                           \
    if (DOST_) { /* phase 1 stage: A of t+2 */                                  \
      int nk = ((T_) + 2) * 32;                                                 \
      async16(ap0 + nk, &As[(((BUF_) + 2) % 3) * 8192 + d0]);                   \
      async16(ap1 + nk, &As[(((BUF_) + 2) % 3) * 8192 + d1]);                   \
    }                                                                           \
    _Pragma("unroll") for (int m = 0; m < 4; ++m)                               \
        a[m] = *(const s16x8*)(Ab + aoff[m]);                                   \
    _Pragma("unroll") for (int n = 0; n < 4; ++n)                               \
        b[n] = *(const s16x8*)(Bb + boff[n]);                                   \
    __builtin_amdgcn_s_setprio(1);                                              \
    _Pragma("unroll") for (int m = 0; m < 4; ++m)                               \
        _Pragma("unroll") for (int n = 0; n < 4; ++n)                           \
            acc[m][n] = __builtin_amdgcn_mfma_f32_16x16x32_bf16(                \
                a[m], b[n], acc[m][n], 0, 0, 0);                                \
    __builtin_amdgcn_s_setprio(0);                                              \
    if (DOST_) { /* phase 2 stage: B of t+2 */                                  \
      int nk = ((T_) + 2) * 32;                                                 \
      async16(bp0 + nk, &Bs[(((BUF_) + 2) % 3) * 8192 + d0]);                   \
      async16(bp1 + nk, &Bs[(((BUF_) + 2) % 3) * 8192 + d1]);                   \
    }                                                                           \
    _Pragma("unroll") for (int m = 4; m < 8; ++m)                               \
        a[m] = *(const s16x8*)(Ab + aoff[m]);                                   \
    __builtin_amdgcn_s_setprio(1);                                              \
    _Pragma("unroll") for (int m = 4; m < 8; ++m)                               \
        _Pragma("unroll") for (int n = 0; n < 4; ++n)                           \
            acc[m][n] = __builtin_amdgcn_mfma_f32_16x16x32_bf16(                \
                a[m], b[n], acc[m][n], 0, 0, 0);                                \
    __builtin_amdgcn_s_setprio(0);                                              \
  }

  for (int tb = 0; tb < 30; tb += 3) {
    G1_STEP(tb, 0, "4", 1)
    G1_STEP(tb + 1, 1, "4", 1)
    G1_STEP(tb + 2, 2, "4", 1)
  }
  G1_STEP(30, 0, "4", 0)
  G1_STEP(31, 1, "0", 0)
#undef G1_STEP

  int g4 = lane >> 4, cl = lane & 15;
  int fbase = (4 * ft + wc) * 32;   // 32 f-cols per wave (w1 n=0,1 ; w3 n=2,3)
#pragma unroll
  for (int m = 0; m < 8; ++m) {
#pragma unroll
    for (int j = 0; j < 4; ++j) {
      int rloc = wr * 128 + m * 16 + g4 * 4 + j;
      if (r0 + rloc < ne) {
        unsigned short* hp = H + (size_t)(hbase + r0 + rloc) * F_DIM + fbase + cl;
#pragma unroll
        for (int n = 0; n < 2; ++n) {
          float c1 = acc[m][n][j], c3 = acc[m][n + 2][j];
          float h = c1 / (1.0f + __expf(-c1)) * c3;
          hp[n * 16] = f2bf(h);
        }
      }
    }
  }
}

// ---- GEMM2: P[slot] = w * (He @ W2e). Plain stores, no atomics ----
__global__ __launch_bounds__(512, 2) void gemm2_kernel(
    const unsigned short* __restrict__ H, const unsigned short* __restrict__ w2t,
    const int* __restrict__ cnt, const int* __restrict__ ilist,
    const float* __restrict__ wlist, float* __restrict__ P) {
  int flat = blockIdx.x;       // 1024 blocks
  int e = flat & 7;
  int widx = flat >> 3;        // 0..127
  int ne = cnt[e];
  int art = (ne + 255) >> 8;
  if (widx >= (art << 2)) return;
  int nt = widx & 3;           // nt-fast: 4 nt share each contiguous H window
  int rt = widx >> 2;
  int r0 = rt * 256;
  int hbase = 0;
#pragma unroll
  for (int j = 0; j < E_NUM; ++j) hbase += (j < e) ? cnt[j] : 0;
  __shared__ __align__(16) unsigned short As[3 * 8192];
  __shared__ __align__(16) unsigned short Bs[3 * 8192];
  __shared__ int toks[256];
  __shared__ float wts[256];
  int tid = threadIdx.x, lane = tid & 63, w = tid >> 6;
  if (tid < 256) {
    int idx = e * T_TOK + min(r0 + tid, ne - 1);
    toks[tid] = ilist[idx];
    wts[tid] = wlist[idx];
  }
  __syncthreads();
  const unsigned short* bpanel = w2t + ((size_t)e * D_DIM + nt * 256) * F_DIM;
  int sr0 = tid >> 2, sr1 = sr0 + 128;
  int ch0 = (((tid & 3) ^ ((sr0 >> 1) & 3)) * 8);
  int ch1 = (((tid & 3) ^ ((sr1 >> 1) & 3)) * 8);
  const unsigned short* ap0 = H + (size_t)(hbase + min(r0 + sr0, ne - 1)) * F_DIM + ch0;
  const unsigned short* ap1 = H + (size_t)(hbase + min(r0 + sr1, ne - 1)) * F_DIM + ch1;
  const unsigned short* bp0 = bpanel + (size_t)sr0 * F_DIM + ch0;
  const unsigned short* bp1 = bpanel + (size_t)sr1 * F_DIM + ch1;
  int d0 = (sr0 * 32) + (tid & 3) * 8;
  int d1 = d0 + 4096;
  int wr = w >> 2, wc = w & 3;
  int lr = lane & 15, lc = lane >> 4;
  int aoff[8], boff[4];
#pragma unroll
  for (int m = 0; m < 8; ++m) {
    int row = wr * 128 + m * 16 + lr;
    aoff[m] = row * 32 + ((lc ^ ((row >> 1) & 3)) * 8);
  }
#pragma unroll
  for (int n = 0; n < 4; ++n) {
    int row = wc * 64 + n * 16 + lr;
    boff[n] = row * 32 + ((lc ^ ((row >> 1) & 3)) * 8);
  }
  f32x4 acc[8][4] = {};
  async16(ap0, &As[d0]); async16(ap1, &As[d1]);
  async16(bp0, &Bs[d0]); async16(bp1, &Bs[d1]);
  async16(ap0 + 32, &As[8192 + d0]); async16(ap1 + 32, &As[8192 + d1]);
  async16(bp0 + 32, &Bs[8192 + d0]); async16(bp1 + 32, &Bs[8192 + d1]);

#define G2_STEP(T_, BUF_, VMC_, DOST_)                                          \
  {                                                                             \
    asm volatile("s_waitcnt vmcnt(" VMC_ ")" ::: "memory");                     \
    __builtin_amdgcn_s_barrier();                                               \
    const unsigned short* Ab = &As[(BUF_) * 8192];                              \
    const unsigned short* Bb = &Bs[(BUF_) * 8192];                              \
    s16x8 a[8], b[4];                                                           \
    if (DOST_) {                                                                \
      int nk = ((T_) + 2) * 32;                                                 \
      async16(ap0 + nk, &As[(((BUF_) + 2) % 3) * 8192 + d0]);                   \
      async16(ap1 + nk, &As[(((BUF_) + 2) % 3) * 8192 + d1]);                   \
    }                                                                           \
    _Pragma("unroll") for (int m = 0; m < 4; ++m)                               \
        a[m] = *(const s16x8*)(Ab + aoff[m]);                                   \
    _Pragma("unroll") for (int n = 0; n < 4; ++n)                               \
        b[n] = *(const s16x8*)(Bb + boff[n]);                                   \
    __builtin_amdgcn_s_setprio(1);                                              \
    _Pragma("unroll") for (int m = 0; m < 4; ++m)                               \
        _Pragma("unroll") for (int n = 0; n < 4; ++n)                           \
            acc[m][n] = __builtin_amdgcn_mfma_f32_16x16x32_bf16(                \
                a[m], b[n], acc[m][n], 0, 0, 0);                                \
    __builtin_amdgcn_s_setprio(0);                                              \
    if (DOST_) {                                                                \
      int nk = ((T_) + 2) * 32;                                                 \
      async16(bp0 + nk, &Bs[(((BUF_) + 2) % 3) * 8192 + d0]);                   \
      async16(bp1 + nk, &Bs[(((BUF_) + 2) % 3) * 8192 + d1]);                   \
    }                                                                           \
    _Pragma("unroll") for (int m = 4; m < 8; ++m)                               \
        a[m] = *(const s16x8*)(Ab + aoff[m]);                                   \
    __builtin_amdgcn_s_setprio(1);                                              \
    _Pragma("unroll") for (int m = 4; m < 8; ++m)                               \
        _Pragma("unroll") for (int n = 0; n < 4; ++n)                           \
            acc[m][n] = __builtin_amdgcn_mfma_f32_16x16x32_bf16(                \
                a[m], b[n], acc[m][n], 0, 0, 0);                                \
    __builtin_amdgcn_s_setprio(0);                                              \
  }

  for (int tb = 0; tb < 126; tb += 3) {
    G2_STEP(tb, 0, "4", 1)
    G2_STEP(tb + 1, 1, "4", 1)
    G2_STEP(tb + 2, 2, "4", 1)
  }
  G2_STEP(126, 0, "4", 0)
  G2_STEP(127, 1, "0", 0)
#undef G2_STEP

  int g4 = lane >> 4, cl = lane & 15;
#pragma unroll
  for (int m = 0; m < 8; ++m) {
#pragma unroll
    for (int j = 0; j < 4; ++j) {
      int rloc = wr * 128 + m * 16 + g4 * 4 + j;
      if (r0 + rloc < ne) {
        int slot = toks[rloc];           // unique writer per slot: plain stores
        float ww = wts[rloc];
        float* pp = P + (size_t)slot * D_DIM + nt * 256 + wc * 64 + cl;
#pragma unroll
        for (int n = 0; n < 4; ++n)
          pp[n * 16] = ww * acc[m][n][j];
      }
    }
  }
}

// ---- combine: out[t] = P[2t] + P[2t+1] (float4, 2M elements) ----
__global__ __launch_bounds__(256) void combine_kernel(
    const float* __restrict__ P, float* __restrict__ out) {
  int i = blockIdx.x * 256 + threadIdx.x;   // float4 index base
#pragma unroll
  for (int k = 0; k < 4; ++k) {
    int idx = i + k * 524288;               // 2048 blocks * 256 thr = 524288
    int t = idx >> 8, c = idx & 255;
    float4 a = ((const float4*)P)[(size_t)(t * 2) * 256 + c];
    float4 b = ((const float4*)P)[(size_t)(t * 2 + 1) * 256 + c];
    float4 o;
    o.x = a.x + b.x; o.y = a.y + b.y; o.z = a.z + b.z; o.w = a.w + b.w;
    ((float4*)out)[idx] = o;
  }
}

extern "C" void kernel_launch(void* const* d_in, const int* in_sizes, int n_in,
                              void* d_out, int out_size, void* d_ws, size_t ws_size,
                              hipStream_t stream) {
  const float* hs = (const float*)d_in[0];
  const float* nw = (const float*)d_in[1];
  const float* gw = (const float*)d_in[2];
  const float* w1 = (const float*)d_in[3];
  const float* w3 = (const float*)d_in[4];
  const float* w2 = (const float*)d_in[5];
  float* out = (float*)d_out;
  float* logits_out = out + (size_t)T_TOK * D_DIM;

  char* ws = (char*)d_ws;
  unsigned short* xb   = (unsigned short*)(ws);                 // 16 MiB bf16 x
  unsigned short* w13t = (unsigned short*)(ws + 16777216ull);   // 128 MiB [E][8192][D]
  unsigned short* w2t  = (unsigned short*)(ws + 150994944ull);  // 64 MiB [E][D][F]
  unsigned short* H    = (unsigned short*)(ws + 218103808ull);  // 128 MiB compacted [2T][F]
  float* P = (float*)(ws + 16777216ull);  // 64 MiB [2T][D] f32 — aliases dead w13t
  int*   ilist = (int*)(ws + 352321536ull);                     // [E][T] int
  float* wlist = (float*)(ws + 352583680ull);                   // [E][T] f32
  int*   cnt   = (int*)(ws + 352845824ull);                     // [E] int

  hipMemsetAsync(cnt, 0, E_NUM * sizeof(int), stream);
  prepass_kernel<<<24576 + T_TOK, 256, 0, stream>>>(
      hs, nw, gw, w1, w3, w2, xb, w13t, w2t, logits_out, cnt, ilist, wlist);
  gemm1_kernel<<<E_NUM * 32 * 32, 512, 0, stream>>>(xb, w13t, H, cnt, ilist);
  gemm2_kernel<<<E_NUM * 32 * 4, 512, 0, stream>>>(H, w2t, cnt, ilist, wlist, P);
  combine_kernel<<<2048, 256, 0, stream>>>(P, out);
}